// Round 10
// baseline (279.464 us; speedup 1.0000x reference)
//
#include <hip/hip_runtime.h>
#include <math.h>

#define NNODES 50000
#define EORIG  800000
#define ETOT   850000     // EORIG + NNODES self loops
#define NBUCK  196        // ceil(NNODES/256) buckets of 256 nodes (bucket = dst>>8)
#define BSTRIDE 5120      // fixed slots per bucket (mean 4352, +12 sigma headroom)
#define P2CHUNK 4096      // edges per partition block
#define NBLK2  ((ETOT + P2CHUNK - 1)/P2CHUNK)   // 208
#define NBLKW  ((256*256 + 64*256 + 255)/256)   // 320 conv blocks

typedef __attribute__((ext_vector_type(8))) short bf8_t;   // 8 bf16 (bits in shorts)
typedef __attribute__((ext_vector_type(8))) unsigned short us8_t;
typedef __attribute__((ext_vector_type(4))) float f4_t;
typedef __attribute__((ext_vector_type(2))) float f2_t;

constexpr float LOG2E = 1.44269504f;

constexpr size_t align256(size_t x){ return (x + 255) & ~size_t(255); }
constexpr size_t OFF_OFFSETS = 0;                                           // N ints
constexpr size_t OFF_DEG     = OFF_OFFSETS + align256((size_t)NNODES*4);    // N ints
constexpr size_t OFF_GCUR    = OFF_DEG     + align256((size_t)NNODES*4);    // NBUCK ints
constexpr size_t OFF_EPACK   = OFF_GCUR    + align256(NBUCK*4);             // NBUCK*BSTRIDE ints
constexpr size_t OFF_SRC     = OFF_EPACK   + align256((size_t)NBUCK*BSTRIDE*4);
constexpr size_t OFF_AS1     = OFF_SRC     + align256((size_t)NBUCK*BSTRIDE*4); // N*8 f32
constexpr size_t OFF_AD1     = OFF_AS1     + align256((size_t)NNODES*8*4);
constexpr size_t OFF_W1T     = OFF_AD1     + align256((size_t)NNODES*8*4);  // 256*256 bf16 (n-major)
constexpr size_t OFF_W2T     = OFF_W1T     + align256(256*256*2);           // 64*256 bf16 (n-major)
constexpr size_t OFF_H1F8    = OFF_W2T     + align256(64*256*2);            // N*256 fp8
constexpr size_t OFF_OUT1B   = OFF_H1F8    + align256((size_t)NNODES*256);  // N*256 bf16
// h2b overlays dead h1f8 after aggregate1
constexpr size_t OFF_H2B     = OFF_H1F8;                                    // N*64 bf16
constexpr size_t OFF_AS2     = OFF_OUT1B   + align256((size_t)NNODES*256*2);
constexpr size_t OFF_AD2     = OFF_AS2     + align256((size_t)NNODES*4);

__device__ __forceinline__ unsigned short f2bf(float f){
    union { float f; unsigned u; } v; v.f = f;
    unsigned r = v.u + 0x7FFF + ((v.u >> 16) & 1);   // RNE
    return (unsigned short)(r >> 16);
}
__device__ __forceinline__ float bf2f(unsigned short s){
    union { unsigned u; float f; } v; v.u = ((unsigned)s) << 16;
    return v.f;
}

// ---------------- prep: multisplit pass + weight transpose (one dispatch) --
// gcur is ZERO-BASED (memset 0 before); bucket base = b*BSTRIDE + old.
// epack = (src<<8) | (dst & 255)

__global__ __launch_bounds__(256) void prep_k(const int* __restrict__ ei, int* __restrict__ gcur,
                                              int* __restrict__ epack,
                                              const float* __restrict__ W1, const float* __restrict__ W2,
                                              short* __restrict__ w1t, short* __restrict__ w2t){
    const int t = threadIdx.x;
    if (blockIdx.x >= NBLK2){
        int o = (blockIdx.x - NBLK2)*256 + t;
        if (o < 256*256){
            int n = o >> 8, k = o & 255;
            w1t[o] = (short)f2bf(W1[k*256 + n]);
        } else {
            int o2 = o - 256*256;
            if (o2 < 64*256){
                int n = o2 >> 8, k = o2 & 255;
                w2t[o2] = (short)f2bf(W2[k*64 + n]);
            }
        }
        return;
    }
    __shared__ int h[NBUCK];    // block hist -> block base per bucket
    __shared__ int r[NBUCK];    // intra-block rank cursor
    for (int i = t; i < NBUCK; i += 256){ h[i] = 0; r[i] = 0; }
    __syncthreads();
    const int base = blockIdx.x * P2CHUNK;
    int srcs[P2CHUNK/256], dsts[P2CHUNK/256];
#pragma unroll
    for (int j = 0; j < P2CHUNK/256; j++){
        int e = base + j*256 + t;
        if (e < ETOT){
            if (e < EORIG){ srcs[j] = ei[e]; dsts[j] = ei[EORIG + e]; }
            else          { srcs[j] = dsts[j] = e - EORIG; }
            atomicAdd(&h[dsts[j] >> 8], 1);
        } else dsts[j] = -1;
    }
    __syncthreads();
    for (int i = t; i < NBUCK; i += 256){
        int c = h[i];
        h[i] = c ? (i*BSTRIDE + atomicAdd(&gcur[i], c)) : 0;
    }
    __syncthreads();
#pragma unroll
    for (int j = 0; j < P2CHUNK/256; j++){
        if (dsts[j] >= 0){
            int b = dsts[j] >> 8;
            int rk = atomicAdd(&r[b], 1);
            epack[h[b] + rk] = (srcs[j] << 8) | (dsts[j] & 255);
        }
    }
}

// one block per bucket -> local CSR in LDS; offsets/deg coalesced.
__global__ __launch_bounds__(256) void p4_csr(const int* __restrict__ gcur, const int* __restrict__ epack,
                                              int* __restrict__ offsets, int* __restrict__ deg_g,
                                              int* __restrict__ srclist){
    __shared__ int deg[256];
    __shared__ int sm[256];
    __shared__ int cur[256];
    const int b = blockIdx.x, t = threadIdx.x;
    const int s0 = b * BSTRIDE, s1 = s0 + gcur[b];
    deg[t] = 0; __syncthreads();
    for (int i = s0 + t; i < s1; i += 256) atomicAdd(&deg[epack[i] & 255], 1);
    __syncthreads();
    int v = deg[t];
    sm[t] = v; __syncthreads();
    for (int off = 1; off < 256; off <<= 1){
        int add = (t >= off) ? sm[t-off] : 0;
        __syncthreads();
        sm[t] += add;
        __syncthreads();
    }
    int excl = sm[t] - v;
    int node = (b << 8) + t;
    if (node < NNODES){ offsets[node] = s0 + excl; deg_g[node] = v; }
    cur[t] = s0 + excl;
    __syncthreads();
    for (int i = s0 + t; i < s1; i += 256){
        int p = epack[i];
        int pos = atomicAdd(&cur[p & 255], 1);
        srclist[pos] = p >> 8;
    }
}

// ---------------- GEMM1 (MFMA): h1f8 = fp8(x @ W1), fused f32->bf16 A-stage
// + fused as1/ad1 epilogue (pre-scaled by log2(e) for exp2-based softmax).
// 128x256 tile, 512 threads = 2x4 waves, BK=32.

__global__ __launch_bounds__(512) void gemm1_mfma(const float* __restrict__ x, const short* __restrict__ w1t,
        const float* __restrict__ a1s, const float* __restrict__ a1d,
        unsigned char* __restrict__ h1f8, float* __restrict__ as1, float* __restrict__ ad1){
    __shared__ short As[128][40];   // +8 pad: 16B-aligned frags, 2-way banks = free
    __shared__ short Bs[256][40];   // Bs[n][k] (from pre-transposed W1T)
    const int t = threadIdx.x;                 // 0..511
    const int lane = t & 63, wave = t >> 6;    // 8 waves
    const int wy = wave >> 2, wx = wave & 3;   // 2 x 4 wave grid
    const int quad = lane >> 4, l15 = lane & 15;
    const int r0 = blockIdx.x * 128;
    const int srow = t >> 2, skoff = (t & 3) * 8;   // srow 0..127
    f4_t zero4 = {0.f,0.f,0.f,0.f};
    f4_t acc[4][4];
#pragma unroll
    for (int i=0;i<4;i++)
#pragma unroll
      for (int j=0;j<4;j++) acc[i][j] = zero4;

    for (int kk = 0; kk < 256; kk += 32){
        float4 xa0 = {0,0,0,0}, xa1 = {0,0,0,0};
        if (r0 + srow < NNODES){
            xa0 = *(const float4*)(x + (size_t)(r0+srow)*256 + kk + skoff);
            xa1 = *(const float4*)(x + (size_t)(r0+srow)*256 + kk + skoff + 4);
        }
        bf8_t b0  = *(const bf8_t*)(w1t + (size_t)(srow      )*256 + kk + skoff);
        bf8_t b1v = *(const bf8_t*)(w1t + (size_t)(srow + 128)*256 + kk + skoff);
        bf8_t a0;
        a0[0]=f2bf(xa0.x); a0[1]=f2bf(xa0.y); a0[2]=f2bf(xa0.z); a0[3]=f2bf(xa0.w);
        a0[4]=f2bf(xa1.x); a0[5]=f2bf(xa1.y); a0[6]=f2bf(xa1.z); a0[7]=f2bf(xa1.w);
        __syncthreads();
        *(bf8_t*)&As[srow     ][skoff] = a0;
        *(bf8_t*)&Bs[srow     ][skoff] = b0;
        *(bf8_t*)&Bs[srow+128][skoff] = b1v;
        __syncthreads();
        bf8_t af[4], bfr[4];
#pragma unroll
        for (int i=0;i<4;i++) af[i]  = *(const bf8_t*)&As[wy*64 + i*16 + l15][quad*8];
#pragma unroll
        for (int j=0;j<4;j++) bfr[j] = *(const bf8_t*)&Bs[wx*64 + j*16 + l15][quad*8];
#pragma unroll
        for (int i=0;i<4;i++)
#pragma unroll
          for (int j=0;j<4;j++)
            acc[i][j] = __builtin_amdgcn_mfma_f32_16x16x32_bf16(af[i], bfr[j], acc[i][j], 0,0,0);
    }
    // epilogue: fp8 store (HW cvt) + fused alpha projections (x log2e)
    const int colbase = wx*64;               // this wave's 64 cols = 2 heads
    const int head0 = colbase >> 5;
    float cs[4], cd[4];
#pragma unroll
    for (int j=0;j<4;j++){
        cs[j] = a1s[colbase + j*16 + l15] * LOG2E;
        cd[j] = a1d[colbase + j*16 + l15] * LOG2E;
    }
#pragma unroll
    for (int i=0;i<4;i++){
        int rowb = r0 + wy*64 + i*16 + quad*4;
#pragma unroll
        for (int reg=0; reg<4; reg++){
            int row = rowb + reg;
            bool valid = row < NNODES;
            float sp0=0.f, dp0=0.f, sp1=0.f, dp1=0.f;
#pragma unroll
            for (int j=0;j<4;j++){
                float v = acc[i][j][reg];
                if (j < 2){ sp0 += v*cs[j]; dp0 += v*cd[j]; }
                else      { sp1 += v*cs[j]; dp1 += v*cd[j]; }
                if (valid){
                    unsigned enc = (unsigned)__builtin_amdgcn_cvt_pk_fp8_f32(v, v, 0, false);
                    h1f8[(size_t)row*256 + colbase + j*16 + l15] = (unsigned char)(enc & 0xffu);
                }
            }
            sp0 += __shfl_xor(sp0,1); sp0 += __shfl_xor(sp0,2); sp0 += __shfl_xor(sp0,4); sp0 += __shfl_xor(sp0,8);
            dp0 += __shfl_xor(dp0,1); dp0 += __shfl_xor(dp0,2); dp0 += __shfl_xor(dp0,4); dp0 += __shfl_xor(dp0,8);
            sp1 += __shfl_xor(sp1,1); sp1 += __shfl_xor(sp1,2); sp1 += __shfl_xor(sp1,4); sp1 += __shfl_xor(sp1,8);
            dp1 += __shfl_xor(dp1,1); dp1 += __shfl_xor(dp1,2); dp1 += __shfl_xor(dp1,4); dp1 += __shfl_xor(dp1,8);
            if (valid && l15 == 0){
                as1[row*8 + head0    ] = sp0;
                ad1[row*8 + head0    ] = dp0;
                as1[row*8 + head0 + 1] = sp1;
                ad1[row*8 + head0 + 1] = dp1;
            }
        }
    }
}

// ---------------- GEMM2 (MFMA): h2b = bf16(out1b @ W2), fused as2/ad2 ------

__global__ __launch_bounds__(256) void gemm2_mfma(const short* __restrict__ ab, const short* __restrict__ w2t,
        const float* __restrict__ a2s, const float* __restrict__ a2d,
        short* __restrict__ h2b, float* __restrict__ as2, float* __restrict__ ad2){
    __shared__ short As[128][40];
    __shared__ short Bs[64][40];
    const int t = threadIdx.x;
    const int lane = t & 63, wave = t >> 6;
    const int quad = lane >> 4, l15 = lane & 15;
    const int r0 = blockIdx.x * 128;
    const int srow = t >> 2, skoff = (t & 3) * 8;
    f4_t zero4 = {0.f,0.f,0.f,0.f};
    f4_t acc[2][4];
#pragma unroll
    for (int i=0;i<2;i++)
#pragma unroll
      for (int j=0;j<4;j++) acc[i][j] = zero4;

    for (int kk = 0; kk < 256; kk += 32){
        bf8_t a0 = {}, a1v = {};
        if (r0 + srow < NNODES)      a0  = *(const bf8_t*)(ab + (size_t)(r0+srow)*256 + kk + skoff);
        if (r0 + srow + 64 < NNODES) a1v = *(const bf8_t*)(ab + (size_t)(r0+srow+64)*256 + kk + skoff);
        bf8_t b0 = *(const bf8_t*)(w2t + (size_t)srow*256 + kk + skoff);   // srow = n (0..63)
        __syncthreads();
        *(bf8_t*)&As[srow   ][skoff] = a0;
        *(bf8_t*)&As[srow+64][skoff] = a1v;
        *(bf8_t*)&Bs[srow   ][skoff] = b0;
        __syncthreads();
        bf8_t af[2], bfr[4];
#pragma unroll
        for (int i=0;i<2;i++) af[i]  = *(const bf8_t*)&As[wave*32 + i*16 + l15][quad*8];
#pragma unroll
        for (int j=0;j<4;j++) bfr[j] = *(const bf8_t*)&Bs[j*16 + l15][quad*8];
#pragma unroll
        for (int i=0;i<2;i++)
#pragma unroll
          for (int j=0;j<4;j++)
            acc[i][j] = __builtin_amdgcn_mfma_f32_16x16x32_bf16(af[i], bfr[j], acc[i][j], 0,0,0);
    }
    float cs[4], cd[4];
#pragma unroll
    for (int j=0;j<4;j++){
        cs[j] = a2s[j*16 + l15] * LOG2E;
        cd[j] = a2d[j*16 + l15] * LOG2E;
    }
#pragma unroll
    for (int i=0;i<2;i++){
        int rowb = r0 + wave*32 + i*16 + quad*4;
#pragma unroll
        for (int reg=0; reg<4; reg++){
            int row = rowb + reg;
            bool valid = row < NNODES;
            float sp=0.f, dp=0.f;
#pragma unroll
            for (int j=0;j<4;j++){
                float v = acc[i][j][reg];
                sp += v*cs[j]; dp += v*cd[j];
                if (valid) h2b[(size_t)row*64 + j*16 + l15] = (short)f2bf(v);
            }
            sp += __shfl_xor(sp,1); sp += __shfl_xor(sp,2); sp += __shfl_xor(sp,4); sp += __shfl_xor(sp,8);
            dp += __shfl_xor(dp,1); dp += __shfl_xor(dp,2); dp += __shfl_xor(dp,4); dp += __shfl_xor(dp,8);
            if (valid && l15 == 0){ as2[row] = sp; ad2[row] = dp; }
        }
    }
}

// ---------------- aggregation: 2 edges per gather instruction ---------------
// agg1: lane loads dwordx2 (8 fp8 ch); 32 lanes/row; epair = lane>>5.
// p dedup: lanes 0..15 compute p(edge=lane>>3, head=lane&7) per pair.

__global__ __launch_bounds__(256) void aggregate1_k(const unsigned char* __restrict__ h1f8,
        const float* __restrict__ as1, const float* __restrict__ ad1,
        const int* __restrict__ offsets, const int* __restrict__ deg_g,
        const int* __restrict__ srclist,
        const float* __restrict__ b1, short* __restrict__ out1b){
    int d = blockIdx.x*4 + (threadIdx.x >> 6);
    int lane = threadIdx.x & 63;
    if (d >= NNODES) return;
    const int q      = lane & 31;          // channels 8q..8q+7
    const int epair  = lane >> 5;          // which edge of each pair this lane gathers
    const int head_q = q >> 2;             // head of these channels
    const int p_head = lane & 7;           // p-lane role (lanes 0..15)
    const int p_edge = (lane >> 3) & 1;
    const int psrc   = (epair << 3) | head_q;
    int start = offsets[d];
    int deg = deg_g[d];
    float ad_p = ad1[d*8 + p_head];
    float denom = 0.f;
    f2_t a0={0,0}, a1={0,0}, a2={0,0}, a3={0,0};
    for (int w = 0; w < deg; w += 64){
        int deg_w = min(64, deg - w);
        int s_reg = srclist[start + w + min(lane, deg_w-1)];
        int ngr = (deg_w + 1) >> 1;
        auto comp_p = [&](int g)->float{
            int ei = g*2 + p_edge;
            int s  = __shfl(s_reg, min(ei, deg_w-1));
            float e = as1[s*8 + p_head] + ad_p;
            e = fmaxf(0.2f*e, e);
            float p = exp2f(e);
            return (ei < deg_w) ? p : 0.f;
        };
        float p_reg = comp_p(0);
        for (int g = 0; g < ngr; g++){
            float p_cur = p_reg;
            if (g + 1 < ngr) p_reg = comp_p(g+1);
            int ei = g*2 + epair;
            int se = __shfl(s_reg, min(ei, deg_w-1));
            float pe = __shfl(p_cur, psrc);            // 0 when ei >= deg_w
            uint2 wv = *(const uint2*)(h1f8 + (size_t)se*256 + q*8);
            f2_t lo0 = __builtin_amdgcn_cvt_pk_f32_fp8(wv.x, false);
            f2_t hi0 = __builtin_amdgcn_cvt_pk_f32_fp8(wv.x, true);
            f2_t lo1 = __builtin_amdgcn_cvt_pk_f32_fp8(wv.y, false);
            f2_t hi1 = __builtin_amdgcn_cvt_pk_f32_fp8(wv.y, true);
            a0 += pe*lo0; a1 += pe*hi0; a2 += pe*lo1; a3 += pe*hi1;
            denom += pe;
        }
    }
    // merge edge-pair halves (lanes q and q+32 hold complementary partials)
    a0[0] += __shfl_xor(a0[0], 32); a0[1] += __shfl_xor(a0[1], 32);
    a1[0] += __shfl_xor(a1[0], 32); a1[1] += __shfl_xor(a1[1], 32);
    a2[0] += __shfl_xor(a2[0], 32); a2[1] += __shfl_xor(a2[1], 32);
    a3[0] += __shfl_xor(a3[0], 32); a3[1] += __shfl_xor(a3[1], 32);
    denom += __shfl_xor(denom, 32);
    if (lane < 32){
        float inv = 1.f / denom;
        float4 bv0 = *(const float4*)(b1 + q*8);
        float4 bv1 = *(const float4*)(b1 + q*8 + 4);
        us8_t us;
        us[0] = f2bf(fmaxf(a0[0]*inv + bv0.x, 0.f));
        us[1] = f2bf(fmaxf(a0[1]*inv + bv0.y, 0.f));
        us[2] = f2bf(fmaxf(a1[0]*inv + bv0.z, 0.f));
        us[3] = f2bf(fmaxf(a1[1]*inv + bv0.w, 0.f));
        us[4] = f2bf(fmaxf(a2[0]*inv + bv1.x, 0.f));
        us[5] = f2bf(fmaxf(a2[1]*inv + bv1.y, 0.f));
        us[6] = f2bf(fmaxf(a3[0]*inv + bv1.z, 0.f));
        us[7] = f2bf(fmaxf(a3[1]*inv + bv1.w, 0.f));
        *(us8_t*)(out1b + (size_t)d*256 + q*8) = us;
    }
}

// agg2: lane loads u32 (2 bf16 ch); 32 lanes/row; 2 edges/instr.
__global__ __launch_bounds__(256) void aggregate2_k(const unsigned short* __restrict__ h2b,
        const float* __restrict__ as2, const float* __restrict__ ad2,
        const int* __restrict__ offsets, const int* __restrict__ deg_g,
        const int* __restrict__ srclist,
        const float* __restrict__ b2, float* __restrict__ out){
    int d = blockIdx.x*4 + (threadIdx.x >> 6);
    int lane = threadIdx.x & 63;
    if (d >= NNODES) return;
    const int q     = lane & 31;       // channels 2q, 2q+1
    const int epair = lane >> 5;
    int start = offsets[d];
    int deg = deg_g[d];
    float ad_v = ad2[d];
    float denom = 0.f;
    f2_t acc = {0.f, 0.f};
    for (int w = 0; w < deg; w += 64){
        int deg_w = min(64, deg - w);
        int s_reg = srclist[start + w + min(lane, deg_w-1)];
        float ev = as2[s_reg] + ad_v;
        ev = fmaxf(0.2f*ev, ev);
        float p_lane = (lane < deg_w) ? exp2f(ev) : 0.f;
        int ngr = (deg_w + 1) >> 1;
        for (int g = 0; g < ngr; g++){
            int ei = g*2 + epair;
            float pe = __shfl(p_lane, min(ei, 63));
            int   se = __shfl(s_reg, min(ei, deg_w-1));
            unsigned u = *(const unsigned*)(h2b + (size_t)se*64 + q*2);
            f2_t hv = { bf2f((unsigned short)(u & 0xffffu)), bf2f((unsigned short)(u >> 16)) };
            acc += pe*hv;
            denom += pe;
        }
    }
    acc[0] += __shfl_xor(acc[0], 32);
    acc[1] += __shfl_xor(acc[1], 32);
    denom  += __shfl_xor(denom, 32);
    float inv = 1.f / denom;
    float2 bvv = *(const float2*)(b2 + q*2);
    float v0 = acc[0]*inv + bvv.x;
    float v1 = acc[1]*inv + bvv.y;
    // log_softmax over 64 values held as 32 lanes x 2 (both halves mirrored)
    float mx = fmaxf(v0, v1);
#pragma unroll
    for (int off = 1; off < 32; off <<= 1) mx = fmaxf(mx, __shfl_xor(mx, off));
    float ss = __expf(v0 - mx) + __expf(v1 - mx);
#pragma unroll
    for (int off = 1; off < 32; off <<= 1) ss += __shfl_xor(ss, off);
    float lg = mx + __logf(ss);
    if (lane < 32){
        float2 o = { v0 - lg, v1 - lg };
        *(float2*)(out + (size_t)d*64 + q*2) = o;
    }
}

// ---------------- launch ----------------

extern "C" void kernel_launch(void* const* d_in, const int* in_sizes, int n_in,
                              void* d_out, int out_size, void* d_ws, size_t ws_size,
                              hipStream_t stream){
    const float* x      = (const float*)d_in[0];
    const int*   ei     = (const int*)  d_in[1];
    const float* W1     = (const float*)d_in[2];
    const float* a_src1 = (const float*)d_in[3];
    const float* a_dst1 = (const float*)d_in[4];
    const float* b1     = (const float*)d_in[5];
    const float* W2     = (const float*)d_in[6];
    const float* a_src2 = (const float*)d_in[7];
    const float* a_dst2 = (const float*)d_in[8];
    const float* b2     = (const float*)d_in[9];

    char* ws = (char*)d_ws;
    int*   offsets = (int*)  (ws + OFF_OFFSETS);
    int*   deg_g   = (int*)  (ws + OFF_DEG);
    int*   gcur    = (int*)  (ws + OFF_GCUR);
    int*   epack   = (int*)  (ws + OFF_EPACK);
    int*   srclist = (int*)  (ws + OFF_SRC);
    float* as1     = (float*)(ws + OFF_AS1);
    float* ad1     = (float*)(ws + OFF_AD1);
    short* w1t     = (short*)(ws + OFF_W1T);
    short* w2t     = (short*)(ws + OFF_W2T);
    unsigned char* h1f8 = (unsigned char*)(ws + OFF_H1F8);
    short* out1b   = (short*)(ws + OFF_OUT1B);
    short* h2b     = (short*)(ws + OFF_H2B);
    float* as2     = (float*)(ws + OFF_AS2);
    float* ad2     = (float*)(ws + OFF_AD2);

    // CSR multisplit + weight prep (overlapped in one dispatch)
    hipMemsetAsync(gcur, 0, NBUCK*sizeof(int), stream);
    prep_k<<<NBLK2 + NBLKW, 256, 0, stream>>>(ei, gcur, epack, W1, W2, w1t, w2t);
    p4_csr<<<NBUCK, 256, 0, stream>>>(gcur, epack, offsets, deg_g, srclist);

    // Layer 1
    gemm1_mfma<<<(NNODES+127)/128, 512, 0, stream>>>(x, w1t, a_src1, a_dst1, h1f8, as1, ad1);
    aggregate1_k<<<(NNODES+3)/4, 256, 0, stream>>>(h1f8, as1, ad1, offsets, deg_g, srclist, b1, out1b);

    // Layer 2
    gemm2_mfma<<<(NNODES+127)/128, 256, 0, stream>>>(out1b, w2t, a_src2, a_dst2, h2b, as2, ad2);
    aggregate2_k<<<(NNODES+3)/4, 256, 0, stream>>>((const unsigned short*)h2b, as2, ad2, offsets, deg_g, srclist, b2, (float*)d_out);
}